// Round 6
// baseline (8658.508 us; speedup 1.0000x reference)
//
#include <hip/hip_runtime.h>

// Problem constants (from reference)
#define T_STEPS 100
#define BATCH   32
#define NIN     512
#define NN      2048
#define AREAS   2

// ALPHA = float(np.exp(-1e-3/1e-2)); cast to f32 at use-site (NEP-50 weak scalar).
#define ALPHA_D 0.9048374180359595

#define MW_WORDS (BATCH * 128)   // words per smask buffer

// ---------------------------------------------------------------------------
// k0: Poisson input spikes for ALL timesteps. f32 compare semantics.
__global__ __launch_bounds__(256)
void k0_xi(const float* __restrict__ rates, const float* __restrict__ noise,
           float* __restrict__ outXi, unsigned* __restrict__ xi_mask)
{
    int el = blockIdx.x * 256 + threadIdx.x;      // exact grid: 1,638,400
    float r = rates[el], nz = noise[el];
    float p = __fmul_rn(r, 0.001f);
    int spike = (nz < p) ? 1 : 0;
    outXi[el] = (float)spike;
    if (spike) {
        int t = el >> 14;
        int b = (el >> 9) & 31;
        int i = el & (NIN - 1);
        atomicOr(&xi_mask[(t * 32 + b) * 16 + (i >> 5)], 1u << (i & 31));
    }
}

// ---------------------------------------------------------------------------
// k_ff: feedforward currents Iff[t][b][a][n], one block per (tb, a).
// Block-uniform mask walk, coalesced Win reads, ascending-i f32 adds.
__global__ __launch_bounds__(256)
void k_ff(const float* __restrict__ Win, const unsigned* __restrict__ xi_mask,
          float* __restrict__ Iff)
{
    const int tb  = blockIdx.x;      // t*32+b
    const int a   = blockIdx.y;
    const int tid = threadIdx.x;     // cols [8*tid, 8*tid+8)

    __shared__ unsigned mws[16];
    if (tid < 16) mws[tid] = xi_mask[tb * 16 + tid];
    __syncthreads();

    const float* Wa = Win + ((size_t)a << 20) + (tid << 3);
    float4 A0 = {0,0,0,0}, A1 = {0,0,0,0};
    for (int w = 0; w < 16; ++w) {
        unsigned mw = mws[w];
        int base_i = w << 5;
        while (mw) {
            int i = base_i + (__ffs(mw) - 1);
            mw &= mw - 1;
            const float* rp = Wa + ((size_t)i << 11);
            float4 w0 = ((const float4*)rp)[0];
            float4 w1 = ((const float4*)rp)[1];
            A0.x += w0.x; A0.y += w0.y; A0.z += w0.z; A0.w += w0.w;
            A1.x += w1.x; A1.y += w1.y; A1.z += w1.z; A1.w += w1.w;
        }
    }
    float* op = Iff + (((size_t)tb * 2 + a) << 11) + (tid << 3);
    ((float4*)op)[0] = A0;
    ((float4*)op)[1] = A1;
}

// ---------------------------------------------------------------------------
// k_steps: PERSISTENT kernel, all 100 steps, NO grid-wide sync.
// Batches are independent dynamical systems; batch b's masks are produced
// and consumed only by its own 16 blocks (mc:8 x a:2). Each group free-runs
// its own t-loop behind a private 16-block barrier (release fetch_add +
// acquire spin). Load imbalance across batches overlaps instead of summing
// (lockstep pays sum_t max_b; free-run pays max_b sum_t), and barrier
// latency hides under the co-resident second block per CU.
// bx%8 == mc keeps the XCD <-> column-chunk weight partitioning of R5.
// Gather = R5's named-register software pipeline (bit-exact ascending adds,
// no arrays -> no scratch spill). V lives in a register across all steps.
// Cooperative launch is used ONLY for the co-residency guarantee.
__global__ __launch_bounds__(256, 2)
void k_steps(const float* __restrict__ Wrec,
             unsigned* __restrict__ smask,      // [3][B][128]
             unsigned* __restrict__ bar,        // [B][16] (64B stride per b)
             const float* __restrict__ Iff,     // [t][b][a][n]
             float* __restrict__ outS)          // out + T*B*NIN
{
    const int tid = threadIdx.x;
    const int bx  = blockIdx.x;        // 0..511
    const int mc  = bx & 7;
    const int b   = (bx >> 3) & 31;
    const int a   = bx >> 8;
    const int m   = mc * 256 + tid;

    __shared__ unsigned short lrec[AREAS * NN];   // 8 KB
    __shared__ unsigned mws[128];
    __shared__ int base[128];
    __shared__ int cnt_rec;

    const float* __restrict__ Wr = Wrec + m;
    const int rr_self = (a << 11) | m;
    const int slot = (a << 3) | mc;    // 0..15 within this batch group
    unsigned* mybar = bar + b * 16;
    float v_state = 0.0f;

    for (int t = 0; t < T_STEPS; ++t) {
        unsigned* prev  = smask + (t % 3) * MW_WORDS + b * 128;
        unsigned* next  = smask + ((t + 1) % 3) * MW_WORDS + b * 128;
        unsigned* clear = smask + ((t + 2) % 3) * MW_WORDS + b * 128;

        // zero the buffer that becomes `next` at t+1 (16 blocks x 8 words)
        if (tid < 8)
            __hip_atomic_store(&clear[slot * 8 + tid], 0u,
                               __ATOMIC_RELAXED, __HIP_MEMORY_SCOPE_AGENT);

        if (tid < 128)
            mws[tid] = __hip_atomic_load(&prev[tid], __ATOMIC_ACQUIRE,
                                         __HIP_MEMORY_SCOPE_AGENT);
        __syncthreads();

        if (tid < 64) {                  // wave-0 shuffle prefix scan
            int c0 = __popc(mws[2 * tid]), c1 = __popc(mws[2 * tid + 1]);
            int c = c0 + c1, incl = c;
            #pragma unroll
            for (int d = 1; d < 64; d <<= 1) {
                int v = __shfl_up(incl, d, 64);
                if (tid >= d) incl += v;
            }
            base[2 * tid]     = incl - c;
            base[2 * tid + 1] = incl - c1;
            if (tid == 63) cnt_rec = incl;
        }
        __syncthreads();
        if (tid < 128 && mws[tid]) {
            int off = base[tid];
            unsigned w = mws[tid];
            int bb = tid << 5;
            while (w) { int p = __ffs(w) - 1; lrec[off++] = (unsigned short)(bb + p); w &= w - 1; }
        }
        __syncthreads();

        const int nrec = cnt_rec;
        unsigned xd = (mws[rr_self >> 5] >> (rr_self & 31)) & 1u;
        float accf = Iff[((((size_t)t * 32 + b) * 2 + a) << 11) + m];

        // ---- recurrent gather: ascending (s,n), serial f32 adds,
        //      2-stage pipeline in NAMED registers (no spill) -------------
#define OFF_OF(rr) (((((rr) >> 11) * 2 + a) << 22) + (((rr) & 2047) << 11))
        float accr = 0.0f;
        int j = 0;
        if (nrec >= 8) {
            uint4 u = *(const uint4*)&lrec[0];
            int o0 = OFF_OF((int)(u.x & 0xffff)), o1 = OFF_OF((int)(u.x >> 16));
            int o2 = OFF_OF((int)(u.y & 0xffff)), o3 = OFF_OF((int)(u.y >> 16));
            int o4 = OFF_OF((int)(u.z & 0xffff)), o5 = OFF_OF((int)(u.z >> 16));
            int o6 = OFF_OF((int)(u.w & 0xffff)), o7 = OFF_OF((int)(u.w >> 16));
            float p0 = Wr[o0], p1 = Wr[o1], p2 = Wr[o2], p3 = Wr[o3];
            float p4 = Wr[o4], p5 = Wr[o5], p6 = Wr[o6], p7 = Wr[o7];
            for (j = 8; j + 8 <= nrec; j += 8) {
                uint4 v = *(const uint4*)&lrec[j];
                int n0 = OFF_OF((int)(v.x & 0xffff)), n1 = OFF_OF((int)(v.x >> 16));
                int n2 = OFF_OF((int)(v.y & 0xffff)), n3 = OFF_OF((int)(v.y >> 16));
                int n4 = OFF_OF((int)(v.z & 0xffff)), n5 = OFF_OF((int)(v.z >> 16));
                int n6 = OFF_OF((int)(v.w & 0xffff)), n7 = OFF_OF((int)(v.w >> 16));
                float q0 = Wr[n0], q1 = Wr[n1], q2 = Wr[n2], q3 = Wr[n3];
                float q4 = Wr[n4], q5 = Wr[n5], q6 = Wr[n6], q7 = Wr[n7];
                accr = __fadd_rn(accr, p0); accr = __fadd_rn(accr, p1);
                accr = __fadd_rn(accr, p2); accr = __fadd_rn(accr, p3);
                accr = __fadd_rn(accr, p4); accr = __fadd_rn(accr, p5);
                accr = __fadd_rn(accr, p6); accr = __fadd_rn(accr, p7);
                p0 = q0; p1 = q1; p2 = q2; p3 = q3;
                p4 = q4; p5 = q5; p6 = q6; p7 = q7;
            }
            accr = __fadd_rn(accr, p0); accr = __fadd_rn(accr, p1);
            accr = __fadd_rn(accr, p2); accr = __fadd_rn(accr, p3);
            accr = __fadd_rn(accr, p4); accr = __fadd_rn(accr, p5);
            accr = __fadd_rn(accr, p6); accr = __fadd_rn(accr, p7);
        }
        for (; j < nrec; ++j) {
            int rr = lrec[j];
            accr = __fadd_rn(accr, Wr[OFF_OF(rr)]);
        }
#undef OFF_OF

        // ---- LIF update, numpy f32 op-for-op ----
        float I  = __fadd_rn(accf, accr);
        float v  = __fmul_rn((float)ALPHA_D, v_state);
        if (xd) v = 0.0f;
        float vn = __fadd_rn(v, I);
        v_state = vn;
        int S = (vn >= 1.0f) ? 1 : 0;
        outS[(size_t)a * (T_STEPS * BATCH * NN) + (((size_t)t * BATCH + b) << 11) + m]
            = (float)S;
        if (S) atomicOr(&next[rr_self >> 5], 1u << (rr_self & 31));

        // ---- private 16-block barrier for this batch group ----
        __threadfence();                 // make ORs/zeros globally visible
        __syncthreads();                 // all threads of block arrived
        if (tid == 0) {
            __hip_atomic_fetch_add(mybar, 1u, __ATOMIC_RELEASE,
                                   __HIP_MEMORY_SCOPE_AGENT);
            unsigned target = 16u * (unsigned)(t + 1);
            while (__hip_atomic_load(mybar, __ATOMIC_ACQUIRE,
                                     __HIP_MEMORY_SCOPE_AGENT) < target)
                __builtin_amdgcn_s_sleep(8);
        }
        __syncthreads();
    }
}

// ---------------------------------------------------------------------------
extern "C" void kernel_launch(void* const* d_in, const int* in_sizes, int n_in,
                              void* d_out, int out_size, void* d_ws, size_t ws_size,
                              hipStream_t stream)
{
    const float* rates = (const float*)d_in[0];
    const float* noise = (const float*)d_in[1];
    const float* Win   = (const float*)d_in[2];
    const float* Wrec  = (const float*)d_in[3];
    float* out = (float*)d_out;

    // workspace layout (bytes):
    //   [0, 204800)          xi_mask uint32[T][B][16]
    //   [204800, 253952)     smask   uint32[3][B][128]
    //   [253952, 256000)     bar     uint32[B][16] (64B stride per batch)
    //   [256000, +52428800)  Iff     float[T][B][A][N]
    char* ws = (char*)d_ws;
    unsigned* xi_mask = (unsigned*)ws;
    unsigned* smask   = (unsigned*)(ws + 204800);
    unsigned* bar     = (unsigned*)(ws + 253952);
    float*    Iff     = (float*)(ws + 256000);

    hipMemsetAsync(d_ws, 0, 256000, stream);    // zero xi_mask + smask + bar

    k0_xi<<<6400, 256, 0, stream>>>(rates, noise, out, xi_mask);
    k_ff<<<dim3(3200, 2), 256, 0, stream>>>(Win, xi_mask, Iff);

    float* outS = out + (size_t)T_STEPS * BATCH * NIN;
    void* args[] = { (void*)&Wrec, (void*)&smask, (void*)&bar,
                     (void*)&Iff, (void*)&outS };
    hipLaunchCooperativeKernel((const void*)k_steps, dim3(512), dim3(256),
                               args, 0, stream);
}

// Round 7
// 1637.980 us; speedup vs baseline: 5.2861x; 5.2861x over previous
//
#include <hip/hip_runtime.h>

// Problem constants (from reference)
#define T_STEPS 100
#define BATCH   32
#define NIN     512
#define NN      2048
#define AREAS   2

// ALPHA = float(np.exp(-1e-3/1e-2)); cast to f32 at use-site (NEP-50 weak scalar).
#define ALPHA_D 0.9048374180359595

#define MW_WORDS (BATCH * 128)   // words per smask buffer

// s_waitcnt imm: vmcnt=0, expcnt=7, lgkmcnt=15  -> wait ONLY on vmem completion
#define WAITCNT_VM0 0x0F70

// ---------------------------------------------------------------------------
// k0: Poisson input spikes for ALL timesteps. f32 compare semantics.
__global__ __launch_bounds__(256)
void k0_xi(const float* __restrict__ rates, const float* __restrict__ noise,
           float* __restrict__ outXi, unsigned* __restrict__ xi_mask)
{
    int el = blockIdx.x * 256 + threadIdx.x;      // exact grid: 1,638,400
    float r = rates[el], nz = noise[el];
    float p = __fmul_rn(r, 0.001f);
    int spike = (nz < p) ? 1 : 0;
    outXi[el] = (float)spike;
    if (spike) {
        int t = el >> 14;
        int b = (el >> 9) & 31;
        int i = el & (NIN - 1);
        atomicOr(&xi_mask[(t * 32 + b) * 16 + (i >> 5)], 1u << (i & 31));
    }
}

// ---------------------------------------------------------------------------
// k_ff: feedforward currents Iff[t][b][a][n], one block per (tb, a).
// Block-uniform mask walk, coalesced Win reads, ascending-i f32 adds.
__global__ __launch_bounds__(256)
void k_ff(const float* __restrict__ Win, const unsigned* __restrict__ xi_mask,
          float* __restrict__ Iff)
{
    const int tb  = blockIdx.x;      // t*32+b
    const int a   = blockIdx.y;
    const int tid = threadIdx.x;     // cols [8*tid, 8*tid+8)

    __shared__ unsigned mws[16];
    if (tid < 16) mws[tid] = xi_mask[tb * 16 + tid];
    __syncthreads();

    const float* Wa = Win + ((size_t)a << 20) + (tid << 3);
    float4 A0 = {0,0,0,0}, A1 = {0,0,0,0};
    for (int w = 0; w < 16; ++w) {
        unsigned mw = mws[w];
        int base_i = w << 5;
        while (mw) {
            int i = base_i + (__ffs(mw) - 1);
            mw &= mw - 1;
            const float* rp = Wa + ((size_t)i << 11);
            float4 w0 = ((const float4*)rp)[0];
            float4 w1 = ((const float4*)rp)[1];
            A0.x += w0.x; A0.y += w0.y; A0.z += w0.z; A0.w += w0.w;
            A1.x += w1.x; A1.y += w1.y; A1.z += w1.z; A1.w += w1.w;
        }
    }
    float* op = Iff + (((size_t)tb * 2 + a) << 11) + (tid << 3);
    ((float4*)op)[0] = A0;
    ((float4*)op)[1] = A1;
}

// ---------------------------------------------------------------------------
// k_steps: PERSISTENT, FENCE-FREE. R6's 4x regression was __threadfence() +
// acquire-scoped spin loads emitting buffer_wbl2/buffer_inv -> per-XCD L2
// flushed every step -> Wrec streamed from L3 at ~7 TB/s instead of L2 at
// ~34.5 TB/s. This version has ZERO cache-maintenance ops in the loop:
// every cross-block word (spike masks, clears, barrier counters) is touched
// ONLY by relaxed atomic RMWs (executed at the coherence point, m20), with
// producer->consumer ordering enforced by an explicit s_waitcnt vmcnt(0)
// before the barrier increment. Plain loads (Wrec, Iff, lrec) stay L2/L1
// cached. Spin polls are atomicAdd(ptr,0) RMWs (a plain load could spin on
// a stale L2 line forever) with s_sleep backoff.
// Batch b's 16 blocks (mc:8 x a:2) free-run their own t-loop behind a
// private barrier: imbalance overlaps (max_b sum_t, not sum_t max_b).
// Gather = R5's named-register pipeline (bit-exact ascending f32 adds).
__global__ __launch_bounds__(256, 2)
void k_steps(const float* __restrict__ Wrec,
             unsigned* __restrict__ smask,      // [3][B][128]
             unsigned* __restrict__ bar,        // [B][16] (64B stride per b)
             const float* __restrict__ Iff,     // [t][b][a][n]
             float* __restrict__ outS)          // out + T*B*NIN
{
    const int tid = threadIdx.x;
    const int bx  = blockIdx.x;        // 0..511
    const int mc  = bx & 7;            // XCD = bx%8 = mc (column-chunk <-> L2)
    const int b   = (bx >> 3) & 31;
    const int a   = bx >> 8;
    const int m   = mc * 256 + tid;

    __shared__ unsigned short lrec[AREAS * NN];   // 8 KB
    __shared__ unsigned mws[128];
    __shared__ int base[128];
    __shared__ int cnt_rec;

    const float* __restrict__ Wr = Wrec + m;
    const int rr_self = (a << 11) | m;
    const int slot = (a << 3) | mc;    // 0..15 within this batch group
    unsigned* mybar = bar + b * 16;
    float v_state = 0.0f;

    for (int t = 0; t < T_STEPS; ++t) {
        unsigned* prev  = smask + (t % 3) * MW_WORDS + b * 128;
        unsigned* next  = smask + ((t + 1) % 3) * MW_WORDS + b * 128;
        unsigned* clear = smask + ((t + 2) % 3) * MW_WORDS + b * 128;

        // zero the buffer that becomes `next` at t+1 (16 blocks x 8 words);
        // RMW at coherence point, completion covered by the waitcnt below.
        if (tid < 8) atomicExch(&clear[slot * 8 + tid], 0u);

        // read prev mask: RMW-or-0 = coherent read (bypasses stale L2 lines)
        if (tid < 128) mws[tid] = atomicOr(&prev[tid], 0u);
        __syncthreads();

        if (tid < 64) {                  // wave-0 shuffle prefix scan
            int c0 = __popc(mws[2 * tid]), c1 = __popc(mws[2 * tid + 1]);
            int c = c0 + c1, incl = c;
            #pragma unroll
            for (int d = 1; d < 64; d <<= 1) {
                int v = __shfl_up(incl, d, 64);
                if (tid >= d) incl += v;
            }
            base[2 * tid]     = incl - c;
            base[2 * tid + 1] = incl - c1;
            if (tid == 63) cnt_rec = incl;
        }
        __syncthreads();
        if (tid < 128 && mws[tid]) {
            int off = base[tid];
            unsigned w = mws[tid];
            int bb = tid << 5;
            while (w) { int p = __ffs(w) - 1; lrec[off++] = (unsigned short)(bb + p); w &= w - 1; }
        }
        __syncthreads();

        const int nrec = cnt_rec;
        unsigned xd = (mws[rr_self >> 5] >> (rr_self & 31)) & 1u;
        float accf = Iff[((((size_t)t * 32 + b) * 2 + a) << 11) + m];

        // ---- recurrent gather: ascending (s,n), serial f32 adds,
        //      2-stage pipeline in NAMED registers (no spill) -------------
#define OFF_OF(rr) (((((rr) >> 11) * 2 + a) << 22) + (((rr) & 2047) << 11))
        float accr = 0.0f;
        int j = 0;
        if (nrec >= 8) {
            uint4 u = *(const uint4*)&lrec[0];
            int o0 = OFF_OF((int)(u.x & 0xffff)), o1 = OFF_OF((int)(u.x >> 16));
            int o2 = OFF_OF((int)(u.y & 0xffff)), o3 = OFF_OF((int)(u.y >> 16));
            int o4 = OFF_OF((int)(u.z & 0xffff)), o5 = OFF_OF((int)(u.z >> 16));
            int o6 = OFF_OF((int)(u.w & 0xffff)), o7 = OFF_OF((int)(u.w >> 16));
            float p0 = Wr[o0], p1 = Wr[o1], p2 = Wr[o2], p3 = Wr[o3];
            float p4 = Wr[o4], p5 = Wr[o5], p6 = Wr[o6], p7 = Wr[o7];
            for (j = 8; j + 8 <= nrec; j += 8) {
                uint4 v = *(const uint4*)&lrec[j];
                int n0 = OFF_OF((int)(v.x & 0xffff)), n1 = OFF_OF((int)(v.x >> 16));
                int n2 = OFF_OF((int)(v.y & 0xffff)), n3 = OFF_OF((int)(v.y >> 16));
                int n4 = OFF_OF((int)(v.z & 0xffff)), n5 = OFF_OF((int)(v.z >> 16));
                int n6 = OFF_OF((int)(v.w & 0xffff)), n7 = OFF_OF((int)(v.w >> 16));
                float q0 = Wr[n0], q1 = Wr[n1], q2 = Wr[n2], q3 = Wr[n3];
                float q4 = Wr[n4], q5 = Wr[n5], q6 = Wr[n6], q7 = Wr[n7];
                accr = __fadd_rn(accr, p0); accr = __fadd_rn(accr, p1);
                accr = __fadd_rn(accr, p2); accr = __fadd_rn(accr, p3);
                accr = __fadd_rn(accr, p4); accr = __fadd_rn(accr, p5);
                accr = __fadd_rn(accr, p6); accr = __fadd_rn(accr, p7);
                p0 = q0; p1 = q1; p2 = q2; p3 = q3;
                p4 = q4; p5 = q5; p6 = q6; p7 = q7;
            }
            accr = __fadd_rn(accr, p0); accr = __fadd_rn(accr, p1);
            accr = __fadd_rn(accr, p2); accr = __fadd_rn(accr, p3);
            accr = __fadd_rn(accr, p4); accr = __fadd_rn(accr, p5);
            accr = __fadd_rn(accr, p6); accr = __fadd_rn(accr, p7);
        }
        for (; j < nrec; ++j) {
            int rr = lrec[j];
            accr = __fadd_rn(accr, Wr[OFF_OF(rr)]);
        }
#undef OFF_OF

        // ---- LIF update, numpy f32 op-for-op ----
        float I  = __fadd_rn(accf, accr);
        float v  = __fmul_rn((float)ALPHA_D, v_state);
        if (xd) v = 0.0f;
        float vn = __fadd_rn(v, I);
        v_state = vn;
        int S = (vn >= 1.0f) ? 1 : 0;
        outS[(size_t)a * (T_STEPS * BATCH * NN) + (((size_t)t * BATCH + b) << 11) + m]
            = (float)S;
        if (S) atomicOr(&next[rr_self >> 5], 1u << (rr_self & 31));

        // ---- private 16-block barrier, NO cache flushes ----
        // all this wave's RMWs (clear-exch, spike-OR) complete at the
        // coherence point before we signal:
        __builtin_amdgcn_s_waitcnt(WAITCNT_VM0);
        __syncthreads();                 // every wave has drained its RMWs
        if (tid == 0) {
            atomicAdd(mybar, 1u);
            unsigned target = 16u * (unsigned)(t + 1);
            while (atomicAdd(mybar, 0u) < target)   // RMW poll: coherent
                __builtin_amdgcn_s_sleep(16);
        }
        __syncthreads();
    }
}

// ---------------------------------------------------------------------------
extern "C" void kernel_launch(void* const* d_in, const int* in_sizes, int n_in,
                              void* d_out, int out_size, void* d_ws, size_t ws_size,
                              hipStream_t stream)
{
    const float* rates = (const float*)d_in[0];
    const float* noise = (const float*)d_in[1];
    const float* Win   = (const float*)d_in[2];
    const float* Wrec  = (const float*)d_in[3];
    float* out = (float*)d_out;

    // workspace layout (bytes):
    //   [0, 204800)          xi_mask uint32[T][B][16]
    //   [204800, 253952)     smask   uint32[3][B][128]
    //   [253952, 256000)     bar     uint32[B][16] (64B stride per batch)
    //   [256000, +52428800)  Iff     float[T][B][A][N]
    char* ws = (char*)d_ws;
    unsigned* xi_mask = (unsigned*)ws;
    unsigned* smask   = (unsigned*)(ws + 204800);
    unsigned* bar     = (unsigned*)(ws + 253952);
    float*    Iff     = (float*)(ws + 256000);

    hipMemsetAsync(d_ws, 0, 256000, stream);    // zero xi_mask + smask + bar

    k0_xi<<<6400, 256, 0, stream>>>(rates, noise, out, xi_mask);
    k_ff<<<dim3(3200, 2), 256, 0, stream>>>(Win, xi_mask, Iff);

    float* outS = out + (size_t)T_STEPS * BATCH * NIN;
    void* args[] = { (void*)&Wrec, (void*)&smask, (void*)&bar,
                     (void*)&Iff, (void*)&outS };
    hipLaunchCooperativeKernel((const void*)k_steps, dim3(512), dim3(256),
                               args, 0, stream);
}